// Round 1
// baseline (6380.933 us; speedup 1.0000x reference)
//
#include <hip/hip_runtime.h>
#include <cstdint>
#include <cstddef>

#define DEV __device__ __forceinline__

// Problem dims
constexpr int Bb = 256, Tt = 96, Ff = 256, Cc = 256, Hh = 512;
constexpr int T2 = 192, FFDc = 64;

// ---------------- workspace layout (in floats) ----------------
constexpr size_t SZ_DATA  = (size_t)Bb * T2 * Cc;          // 12,582,912
constexpr size_t SZ_QKV   = (size_t)Bb * T2 * 3 * Cc;      // 37,748,736
constexpr size_t OFF_DATA = 0;
constexpr size_t OFF_CTX  = OFF_DATA + SZ_DATA;
constexpr size_t OFF_QKV  = OFF_CTX + SZ_DATA;
// overlays inside the qkv region:
constexpr size_t OFF_DF   = OFF_QKV;                                  // B*T*F  (pre-qkv lifetime)
constexpr size_t OFF_GAMH = OFF_QKV;                                  // B*T*H  (post-attn lifetime)
constexpr size_t OFF_BETA = OFF_QKV + (size_t)Bb * Tt * Hh;           // B*T*F
constexpr size_t OFF_T1   = OFF_BETA + (size_t)Bb * Tt * Ff;          // B*T2*64 (post-attn)
// small buffers
constexpr size_t OFF_S    = OFF_QKV + SZ_QKV;
constexpr size_t OFF_H    = OFF_S;                                    // 131072
constexpr size_t OFF_DBAR = OFF_H    + (size_t)Bb * Hh;               // 65536
constexpr size_t OFF_XHP  = OFF_DBAR + (size_t)Bb * Cc;               // 2*65536
constexpr size_t OFF_GHP  = OFF_XHP  + 2 * (size_t)Bb * Ff;           // 2*393216
constexpr size_t OFF_XUP  = OFF_GHP  + 2 * (size_t)Bb * 3 * Hh;       // 4*65536
constexpr size_t OFF_XI   = OFF_XUP  + 4 * (size_t)Bb * Ff;           // 65536
constexpr size_t OFF_GIP  = OFF_XI   + (size_t)Bb * Ff;               // 2*393216
constexpr size_t OFF_LOSSP= OFF_GIP  + 2 * (size_t)Bb * 3 * Hh;       // 256
constexpr size_t OFF_DEN  = OFF_LOSSP + 256;                          // 128
constexpr size_t OFF_SW   = OFF_DEN + 128;                            // 4
constexpr size_t OFF_LOSS = OFF_SW + 4;                               // 4
constexpr size_t WS_FLOATS = OFF_LOSS + 4;

// ---------------- generic fp32 tiled GEMM body ----------------
// C tile = 64 x (16*TN); 256 threads; micro 4xTN; K must be multiple of 16.
// A is (M,K)-like via loadA(m,k); B is (N,K)-like via loadB(n,k).
template<int TN, class FA, class FB, class FE>
DEV void gemm_body(int kBegin, int kEnd, FA loadA, FB loadB, FE epi) {
  constexpr int BN = 16 * TN;
  __shared__ float As[16][68];
  __shared__ float Bs[16][BN + 4];
  const int tid = threadIdx.x;
  const int m0 = blockIdx.y * 64;
  const int n0 = blockIdx.x * BN;
  const int ty = tid >> 4, tx = tid & 15;
  float acc[4][TN];
#pragma unroll
  for (int i = 0; i < 4; i++)
#pragma unroll
    for (int j = 0; j < TN; j++) acc[i][j] = 0.f;

  for (int k0 = kBegin; k0 < kEnd; k0 += 16) {
    {
      const int lr = tid >> 2, lc = (tid & 3) * 4;
#pragma unroll
      for (int i = 0; i < 4; i++) As[lc + i][lr] = loadA(m0 + lr, k0 + lc + i);
    }
    if constexpr (TN == 4) {
      const int lr = tid >> 2, lc = (tid & 3) * 4;
#pragma unroll
      for (int i = 0; i < 4; i++) Bs[lc + i][lr] = loadB(n0 + lr, k0 + lc + i);
    } else {
      const int lr = tid >> 1, lc = (tid & 1) * 8;
#pragma unroll
      for (int i = 0; i < 8; i++) Bs[lc + i][lr] = loadB(n0 + lr, k0 + lc + i);
    }
    __syncthreads();
#pragma unroll
    for (int kk = 0; kk < 16; kk++) {
      float a[4], b[TN];
      float4 av = *(const float4*)&As[kk][ty * 4];
      a[0] = av.x; a[1] = av.y; a[2] = av.z; a[3] = av.w;
#pragma unroll
      for (int j = 0; j < TN; j += 4) {
        float4 bv = *(const float4*)&Bs[kk][tx * TN + j];
        b[j] = bv.x; b[j + 1] = bv.y; b[j + 2] = bv.z; b[j + 3] = bv.w;
      }
#pragma unroll
      for (int i = 0; i < 4; i++)
#pragma unroll
        for (int j = 0; j < TN; j++)
          acc[i][j] = fmaf(a[i], b[j], acc[i][j]);
    }
    __syncthreads();
  }
  epi(acc, m0 + ty * 4, n0 + tx * TN);
}

DEV float sigmoidf_(float v) { return 1.f / (1.f + __expf(-v)); }

// ---------------- front-end kernels ----------------

// decay_factor = 0.5*(1 - tanh(sign(dd)*|dd@Wo^T + bo|)), dd = deltas - intervals
__global__ __launch_bounds__(256) void k_decay(const float* __restrict__ deltas,
    const float* __restrict__ intervals, const float* __restrict__ Wo,
    const float* __restrict__ bo, float* __restrict__ df) {
  gemm_body<8>(0, 256,
    [&](int m, int k) { return deltas[(size_t)m * 256 + k] - intervals[k]; },
    [&](int n, int k) { return Wo[(size_t)n * 256 + k]; },
    [&](auto& acc, int mb, int nb) {
#pragma unroll
      for (int ii = 0; ii < 4; ii++)
#pragma unroll
        for (int jj = 0; jj < 8; jj++) {
          int m = mb + ii, n = nb + jj;
          float wd = acc[ii][jj] + bo[n];
          float dd = deltas[(size_t)m * 256 + n] - intervals[n];
          float sg = (dd > 0.f) ? 1.f : ((dd < 0.f) ? -1.f : 0.f);
          df[(size_t)m * 256 + n] = 0.5f * (1.f - tanhf(sg * fabsf(wd)));
        }
    });
}

// data half: A @ Wip^T + bip + pe -> data[(b*192 + hlf*96 + t)*256 + n]
__global__ __launch_bounds__(256) void k_proj(const float* __restrict__ A,
    const float* __restrict__ Wip, const float* __restrict__ bip,
    float* __restrict__ data, int hlf) {
  gemm_body<8>(0, 256,
    [&](int m, int k) { return A[(size_t)m * 256 + k]; },
    [&](int n, int k) { return Wip[(size_t)n * 256 + k]; },
    [&](auto& acc, int mb, int nb) {
#pragma unroll
      for (int ii = 0; ii < 4; ii++)
#pragma unroll
        for (int jj = 0; jj < 8; jj++) {
          int m = mb + ii, n = nb + jj;
          int b = m / 96, t = m % 96;
          float freq = __expf((float)(-(n & ~1)) * (9.210340371976184f / 256.f));
          float arg = (float)t * freq;
          float pe = (n & 1) ? cosf(arg) : sinf(arg);
          data[((size_t)b * 192 + hlf * 96 + t) * 256 + n] = acc[ii][jj] + bip[n] + pe;
        }
    });
}

__global__ __launch_bounds__(256) void k_qkv(const float* __restrict__ data,
    const float* __restrict__ Wqkv, const float* __restrict__ bqkv, float* __restrict__ qkv) {
  gemm_body<8>(0, 256,
    [&](int m, int k) { return data[(size_t)m * 256 + k]; },
    [&](int n, int k) { return Wqkv[(size_t)n * 256 + k]; },
    [&](auto& acc, int mb, int nb) {
#pragma unroll
      for (int ii = 0; ii < 4; ii++)
#pragma unroll
        for (int jj = 0; jj < 8; jj++) {
          int m = mb + ii, n = nb + jj;
          qkv[(size_t)m * 768 + n] = acc[ii][jj] + bqkv[n];
        }
    });
}

// Attention over BATCH axis: per (l,h): S = Q K^T/sqrt(32) (256x256), softmax rows, ctx = P V.
// One block handles a 64-row i-block; online softmax over 4 j-blocks of 64.
__global__ __launch_bounds__(256) void k_attn(const float* __restrict__ qkv, float* __restrict__ ctx) {
  const int bid = blockIdx.x;           // ((l*8+h)*4 + rb)
  const int rb = bid & 3;
  const int h  = (bid >> 2) & 7;
  const int l  = bid >> 5;
  __shared__ float Qs[32][68];
  __shared__ float Ks[32][68];
  __shared__ float Vs[64][36];
  __shared__ float St[64][68];
  __shared__ float mrow[64], lrow[64], fscale[64], red[4][64];
  const int tid = threadIdx.x;
  // load Q block: Qs[d][i]
  {
    int i = tid & 63, dg = tid >> 6;
    const float* src = qkv + ((size_t)(rb * 64 + i) * 192 + l) * 768 + h * 32 + dg * 8;
    float4 v0 = *(const float4*)src;
    float4 v1 = *(const float4*)(src + 4);
    int d0 = dg * 8;
    Qs[d0 + 0][i] = v0.x; Qs[d0 + 1][i] = v0.y; Qs[d0 + 2][i] = v0.z; Qs[d0 + 3][i] = v0.w;
    Qs[d0 + 4][i] = v1.x; Qs[d0 + 5][i] = v1.y; Qs[d0 + 6][i] = v1.z; Qs[d0 + 7][i] = v1.w;
  }
  if (tid < 64) { mrow[tid] = -1e30f; lrow[tid] = 0.f; }
  float accO[4][4] = {{0.f}};
  const int sm_i = tid & 63, sm_jq = tid >> 6;
  const int pv_i0 = (tid & 15) * 4, pv_d0 = ((tid >> 4) & 7) * 4;
  const bool pv_on = tid < 128;

  for (int jb = 0; jb < 4; jb++) {
    // load K,V block (64 batch rows)
    {
      int j = tid & 63, dg = tid >> 6;
      const float* srcK = qkv + ((size_t)(jb * 64 + j) * 192 + l) * 768 + 256 + h * 32 + dg * 8;
      float4 v0 = *(const float4*)srcK;
      float4 v1 = *(const float4*)(srcK + 4);
      int d0 = dg * 8;
      Ks[d0 + 0][j] = v0.x; Ks[d0 + 1][j] = v0.y; Ks[d0 + 2][j] = v0.z; Ks[d0 + 3][j] = v0.w;
      Ks[d0 + 4][j] = v1.x; Ks[d0 + 5][j] = v1.y; Ks[d0 + 6][j] = v1.z; Ks[d0 + 7][j] = v1.w;
      const float* srcV = srcK + 256;
      float4 w0 = *(const float4*)srcV;
      float4 w1 = *(const float4*)(srcV + 4);
      *(float4*)&Vs[j][d0] = w0;
      *(float4*)&Vs[j][d0 + 4] = w1;
    }
    __syncthreads();
    // QK^T: St[j][i]
    {
      const int j0 = (tid >> 4) * 4, i0 = (tid & 15) * 4;
      float sacc[4][4] = {{0.f}};
#pragma unroll
      for (int k = 0; k < 32; k++) {
        float4 a = *(const float4*)&Ks[k][j0];
        float4 b = *(const float4*)&Qs[k][i0];
        float aa[4] = {a.x, a.y, a.z, a.w}, bb[4] = {b.x, b.y, b.z, b.w};
#pragma unroll
        for (int jj = 0; jj < 4; jj++)
#pragma unroll
          for (int ii = 0; ii < 4; ii++)
            sacc[jj][ii] = fmaf(aa[jj], bb[ii], sacc[jj][ii]);
      }
#pragma unroll
      for (int jj = 0; jj < 4; jj++)
#pragma unroll
        for (int ii = 0; ii < 4; ii++)
          St[j0 + jj][i0 + ii] = sacc[jj][ii] * 0.17677669529663687f;
    }
    __syncthreads();
    // online softmax update
    float pm = -1e30f;
#pragma unroll
    for (int jj = 0; jj < 16; jj++) pm = fmaxf(pm, St[sm_jq * 16 + jj][sm_i]);
    red[sm_jq][sm_i] = pm;
    __syncthreads();
    float m_new = fmaxf(mrow[sm_i], fmaxf(fmaxf(red[0][sm_i], red[1][sm_i]), fmaxf(red[2][sm_i], red[3][sm_i])));
    __syncthreads();
    float psum = 0.f;
#pragma unroll
    for (int jj = 0; jj < 16; jj++) {
      float e = __expf(St[sm_jq * 16 + jj][sm_i] - m_new);
      St[sm_jq * 16 + jj][sm_i] = e;
      psum += e;
    }
    red[sm_jq][sm_i] = psum;
    if (sm_jq == 0) fscale[sm_i] = __expf(mrow[sm_i] - m_new);
    __syncthreads();
    if (sm_jq == 0) {
      lrow[sm_i] = lrow[sm_i] * fscale[sm_i] + red[0][sm_i] + red[1][sm_i] + red[2][sm_i] + red[3][sm_i];
      mrow[sm_i] = m_new;
    }
    // PV accumulate (threads < 128)
    if (pv_on) {
#pragma unroll
      for (int ii = 0; ii < 4; ii++) {
        float f = fscale[pv_i0 + ii];
#pragma unroll
        for (int dd = 0; dd < 4; dd++) accO[ii][dd] *= f;
      }
      for (int j = 0; j < 64; j++) {
        float4 a = *(const float4*)&St[j][pv_i0];
        float4 b = *(const float4*)&Vs[j][pv_d0];
        float aa[4] = {a.x, a.y, a.z, a.w}, bb[4] = {b.x, b.y, b.z, b.w};
#pragma unroll
        for (int ii = 0; ii < 4; ii++)
#pragma unroll
          for (int dd = 0; dd < 4; dd++)
            accO[ii][dd] = fmaf(aa[ii], bb[dd], accO[ii][dd]);
      }
    }
    __syncthreads();
  }
  if (pv_on) {
#pragma unroll
    for (int ii = 0; ii < 4; ii++) {
      float inv = 1.f / lrow[pv_i0 + ii];
#pragma unroll
      for (int dd = 0; dd < 4; dd++)
        ctx[((size_t)(rb * 64 + pv_i0 + ii) * 192 + l) * 256 + h * 32 + pv_d0 + dd] = accO[ii][dd] * inv;
    }
  }
}

// data += ctx @ Wao^T + bao  (in place on data)
__global__ __launch_bounds__(256) void k_attnout(const float* __restrict__ ctx,
    const float* __restrict__ Wao, const float* __restrict__ bao, float* __restrict__ data) {
  gemm_body<8>(0, 256,
    [&](int m, int k) { return ctx[(size_t)m * 256 + k]; },
    [&](int n, int k) { return Wao[(size_t)n * 256 + k]; },
    [&](auto& acc, int mb, int nb) {
#pragma unroll
      for (int ii = 0; ii < 4; ii++)
#pragma unroll
        for (int jj = 0; jj < 8; jj++) {
          int m = mb + ii, n = nb + jj;
          data[(size_t)m * 256 + n] += acc[ii][jj] + bao[n];
        }
    });
}

__global__ __launch_bounds__(256) void k_ln(float* __restrict__ data,
    const float* __restrict__ g, const float* __restrict__ b) {
  int row = blockIdx.x * 4 + (threadIdx.x >> 6);
  int lane = threadIdx.x & 63;
  float* p = data + (size_t)row * 256;
  float4 v = *(float4*)&p[lane * 4];
  float s = v.x + v.y + v.z + v.w;
  float q = v.x * v.x + v.y * v.y + v.z * v.z + v.w * v.w;
  for (int o = 32; o >= 1; o >>= 1) { s += __shfl_xor(s, o); q += __shfl_xor(q, o); }
  float mu = s * (1.f / 256.f);
  float var = q * (1.f / 256.f) - mu * mu;
  float inv = rsqrtf(var + 1e-5f);
  int c = lane * 4;
  v.x = (v.x - mu) * inv * g[c + 0] + b[c + 0];
  v.y = (v.y - mu) * inv * g[c + 1] + b[c + 1];
  v.z = (v.z - mu) * inv * g[c + 2] + b[c + 2];
  v.w = (v.w - mu) * inv * g[c + 3] + b[c + 3];
  *(float4*)&p[lane * 4] = v;
}

__global__ __launch_bounds__(256) void k_ff1(const float* __restrict__ data,
    const float* __restrict__ W1, const float* __restrict__ b1, float* __restrict__ t1) {
  gemm_body<4>(0, 256,
    [&](int m, int k) { return data[(size_t)m * 256 + k]; },
    [&](int n, int k) { return W1[(size_t)n * 256 + k]; },
    [&](auto& acc, int mb, int nb) {
#pragma unroll
      for (int ii = 0; ii < 4; ii++)
#pragma unroll
        for (int jj = 0; jj < 4; jj++) {
          int m = mb + ii, n = nb + jj;
          float v = acc[ii][jj] + b1[n];
          v = 0.5f * v * (1.f + erff(v * 0.7071067811865476f));
          t1[(size_t)m * 64 + n] = v;
        }
    });
}

__global__ __launch_bounds__(256) void k_ff2(const float* __restrict__ t1,
    const float* __restrict__ W2, const float* __restrict__ b2, float* __restrict__ data) {
  gemm_body<8>(0, 64,
    [&](int m, int k) { return t1[(size_t)m * 64 + k]; },
    [&](int n, int k) { return W2[(size_t)n * 64 + k]; },
    [&](auto& acc, int mb, int nb) {
#pragma unroll
      for (int ii = 0; ii < 4; ii++)
#pragma unroll
        for (int jj = 0; jj < 8; jj++) {
          int m = mb + ii, n = nb + jj;
          data[(size_t)m * 256 + n] += acc[ii][jj] + b2[n];
        }
    });
}

__global__ __launch_bounds__(256) void k_dbar(const float* __restrict__ data,
    const float* __restrict__ wop2, float* __restrict__ dbar, float* __restrict__ sw) {
  int b = blockIdx.x, c = threadIdx.x;
  float acc = 0.f;
  for (int lq = 0; lq < 192; lq++) acc += wop2[lq] * data[((size_t)b * 192 + lq) * 256 + c];
  dbar[(size_t)b * 256 + c] = acc;
  if (b == 0 && c == 0) {
    float s = 0.f;
    for (int lq = 0; lq < 192; lq++) s += wop2[lq];
    sw[0] = s;
  }
}

__global__ __launch_bounds__(256) void k_h0(const float* __restrict__ dbar,
    const float* __restrict__ Wop1, const float* __restrict__ bop1,
    const float* __restrict__ bop2, const float* __restrict__ sw, float* __restrict__ h) {
  gemm_body<4>(0, 256,
    [&](int m, int k) { return dbar[(size_t)m * 256 + k]; },
    [&](int n, int k) { return Wop1[(size_t)n * 256 + k]; },
    [&](auto& acc, int mb, int nb) {
#pragma unroll
      for (int ii = 0; ii < 4; ii++)
#pragma unroll
        for (int jj = 0; jj < 4; jj++) {
          int m = mb + ii, n = nb + jj;
          h[(size_t)m * 512 + n] = acc[ii][jj] + sw[0] * bop1[n] + bop2[0];
        }
    });
}

// gamma_h for all (b,t): exp(-relu(deltas @ Wdh^T + bdh))
__global__ __launch_bounds__(256) void k_gamh(const float* __restrict__ deltas,
    const float* __restrict__ Wdh, const float* __restrict__ bdh, float* __restrict__ gamH) {
  gemm_body<8>(0, 256,
    [&](int m, int k) { return deltas[(size_t)m * 256 + k]; },
    [&](int n, int k) { return Wdh[(size_t)n * 256 + k]; },
    [&](auto& acc, int mb, int nb) {
#pragma unroll
      for (int ii = 0; ii < 4; ii++)
#pragma unroll
        for (int jj = 0; jj < 8; jj++) {
          int m = mb + ii, n = nb + jj;
          gamH[(size_t)m * 512 + n] = __expf(-fmaxf(acc[ii][jj] + bdh[n], 0.f));
        }
    });
}

// beta for all (b,t): concat(gamma_x, mask) @ Wwc^T + bwc
__global__ __launch_bounds__(256) void k_beta(const float* __restrict__ deltas,
    const float* __restrict__ mask, const float* __restrict__ wdx, const float* __restrict__ bdx,
    const float* __restrict__ Wwc, const float* __restrict__ bwc, float* __restrict__ beta) {
  gemm_body<8>(0, 512,
    [&](int m, int k) {
      if (k < 256) {
        float d = deltas[(size_t)m * 256 + k];
        return __expf(-fmaxf(fmaf(d, wdx[k], bdx[k]), 0.f));
      }
      return mask[(size_t)m * 256 + (k - 256)];
    },
    [&](int n, int k) { return Wwc[(size_t)n * 512 + k]; },
    [&](auto& acc, int mb, int nb) {
#pragma unroll
      for (int ii = 0; ii < 4; ii++)
#pragma unroll
        for (int jj = 0; jj < 8; jj++) {
          int m = mb + ii, n = nb + jj;
          beta[(size_t)m * 256 + n] = acc[ii][jj] + bwc[n];
        }
    });
}

__global__ __launch_bounds__(256) void k_den(const float* __restrict__ mask, float* __restrict__ den) {
  int t = blockIdx.x, tid = threadIdx.x;
  float s = 0.f;
  for (int idx = tid; idx < 256 * 256; idx += 256) {
    int b = idx >> 8, f = idx & 255;
    s += mask[((size_t)b * 96 + t) * 256 + f];
  }
  for (int o = 32; o >= 1; o >>= 1) s += __shfl_xor(s, o);
  __shared__ float rs[4];
  if ((tid & 63) == 0) rs[tid >> 6] = s;
  __syncthreads();
  if (tid == 0) den[t] = rs[0] + rs[1] + rs[2] + rs[3] + 1e-12f;
}

// ---------------- sequential loop kernels ----------------

// P1: [x_h | gh] = (h*gamma_h) @ [Wh ; Whh]^T   (K-split over z)
__global__ __launch_bounds__(256) void k_p1(const float* __restrict__ h,
    const float* __restrict__ gamH, const float* __restrict__ Wh, const float* __restrict__ Whh,
    float* __restrict__ xh_p, float* __restrict__ gh_p, int t) {
  const int z = blockIdx.z;
  gemm_body<4>(z * 256, z * 256 + 256,
    [&](int m, int k) { return h[(size_t)m * 512 + k] * gamH[((size_t)m * 96 + t) * 512 + k]; },
    [&](int n, int k) { return (n < 256) ? Wh[(size_t)n * 512 + k] : Whh[(size_t)(n - 256) * 512 + k]; },
    [&](auto& acc, int mb, int nb) {
#pragma unroll
      for (int ii = 0; ii < 4; ii++)
#pragma unroll
        for (int jj = 0; jj < 4; jj++) {
          int m = mb + ii, n = nb + jj;
          if (n < 256) xh_p[(size_t)z * 65536 + (size_t)m * 256 + n] = acc[ii][jj];
          else gh_p[(size_t)z * 393216 + (size_t)m * 1536 + (n - 256)] = acc[ii][jj];
        }
    });
}

// P2: xu partials = x_r @ Wfr_masked^T (K-split z in 0..3)
__global__ __launch_bounds__(256) void k_p2(const float* __restrict__ mask,
    const float* __restrict__ x, const float* __restrict__ xh_p, const float* __restrict__ bh,
    const float* __restrict__ Wfr, float* __restrict__ xu_p, int t) {
  const int z = blockIdx.z;
  gemm_body<4>(z * 64, z * 64 + 64,
    [&](int m, int k) {
      size_t i3 = ((size_t)m * 96 + t) * 256 + k;
      float mk = mask[i3];
      float xh = xh_p[(size_t)m * 256 + k] + xh_p[65536 + (size_t)m * 256 + k] + bh[k];
      return mk * x[i3] + (1.f - mk) * xh;
    },
    [&](int n, int k) { float w = Wfr[(size_t)n * 256 + k]; return (n == k) ? 0.f : w; },
    [&](auto& acc, int mb, int nb) {
#pragma unroll
      for (int ii = 0; ii < 4; ii++)
#pragma unroll
        for (int jj = 0; jj < 4; jj++) {
          int m = mb + ii, n = nb + jj;
          xu_p[(size_t)z * 65536 + (size_t)m * 256 + n] = acc[ii][jj];
        }
    });
}

// P2b: x_comb, x_imp, outputs, loss partials
__global__ __launch_bounds__(256) void k_p2b(const float* __restrict__ xu_p,
    const float* __restrict__ xh_p, const float* __restrict__ bh, const float* __restrict__ bfr,
    const float* __restrict__ beta, const float* __restrict__ mask, const float* __restrict__ x,
    float* __restrict__ out_ximp, float* __restrict__ out_rec, float* __restrict__ xi,
    float* __restrict__ lossp, int t) {
  int e = blockIdx.x * 256 + threadIdx.x;
  int m = e >> 8, f = e & 255;
  size_t i3 = ((size_t)m * 96 + t) * 256 + f;
  float xu = xu_p[e] + xu_p[65536 + e] + xu_p[131072 + e] + xu_p[196608 + e] + bfr[f];
  float xh = xh_p[e] + xh_p[65536 + e] + bh[f];
  float bt = beta[i3];
  float xc = bt * xu + (1.f - bt) * xh;
  float mk = mask[i3], xv = x[i3];
  float xim = mk * xv + (1.f - mk) * xc;
  out_ximp[i3] = xim;
  out_rec[i3] = xc;
  xi[e] = xim;
  float pl = fabsf(xc - xv) * mk;
  for (int o = 32; o >= 1; o >>= 1) pl += __shfl_xor(pl, o);
  __shared__ float rs[4];
  if ((threadIdx.x & 63) == 0) rs[threadIdx.x >> 6] = pl;
  __syncthreads();
  if (threadIdx.x == 0) lossp[blockIdx.x] = rs[0] + rs[1] + rs[2] + rs[3];
}

// P3: gi partials = concat(x_imp, mask) @ Wih^T (K=512, split z in 0..1)
__global__ __launch_bounds__(256) void k_p3(const float* __restrict__ xi,
    const float* __restrict__ mask, const float* __restrict__ Wih,
    float* __restrict__ gi_p, int t) {
  const int z = blockIdx.z;
  gemm_body<4>(z * 256, z * 256 + 256,
    [&](int m, int k) {
      if (k < 256) return xi[(size_t)m * 256 + k];
      return mask[((size_t)m * 96 + t) * 256 + (k - 256)];
    },
    [&](int n, int k) { return Wih[(size_t)n * 512 + k]; },
    [&](auto& acc, int mb, int nb) {
#pragma unroll
      for (int ii = 0; ii < 4; ii++)
#pragma unroll
        for (int jj = 0; jj < 4; jj++) {
          int m = mb + ii, n = nb + jj;
          gi_p[(size_t)z * 393216 + (size_t)m * 1536 + n] = acc[ii][jj];
        }
    });
}

// PD: GRU update (blocks 0..511) + deterministic loss reduce (block 512)
__global__ __launch_bounds__(256) void k_pd(float* __restrict__ h,
    const float* __restrict__ gamH, const float* __restrict__ gi_p, const float* __restrict__ gh_p,
    const float* __restrict__ bih, const float* __restrict__ bhh,
    const float* __restrict__ lossp, float* __restrict__ lossacc,
    const float* __restrict__ den, int t) {
  if (blockIdx.x == 512) {
    float s = lossp[threadIdx.x];
    for (int o = 32; o >= 1; o >>= 1) s += __shfl_xor(s, o);
    __shared__ float rs[4];
    if ((threadIdx.x & 63) == 0) rs[threadIdx.x >> 6] = s;
    __syncthreads();
    if (threadIdx.x == 0) lossacc[0] += (rs[0] + rs[1] + rs[2] + rs[3]) / den[t];
    return;
  }
  int e = blockIdx.x * 256 + threadIdx.x;   // 0..131071
  int m = e >> 9, j = e & 511;
  float gam = gamH[((size_t)m * 96 + t) * 512 + j];
  float hd = h[e] * gam;
  size_t b0 = (size_t)m * 1536 + j;
  float ir  = gi_p[b0]        + gi_p[393216 + b0]        + bih[j];
  float iz  = gi_p[b0 + 512]  + gi_p[393216 + b0 + 512]  + bih[j + 512];
  float in_ = gi_p[b0 + 1024] + gi_p[393216 + b0 + 1024] + bih[j + 1024];
  float hr  = gh_p[b0]        + gh_p[393216 + b0]        + bhh[j];
  float hz  = gh_p[b0 + 512]  + gh_p[393216 + b0 + 512]  + bhh[j + 512];
  float hn  = gh_p[b0 + 1024] + gh_p[393216 + b0 + 1024] + bhh[j + 1024];
  float r = sigmoidf_(ir + hr);
  float z = sigmoidf_(iz + hz);
  float nn = tanhf(in_ + r * hn);
  h[e] = (1.f - z) * nn + z * hd;
}

// ---------------- host launcher ----------------
extern "C" void kernel_launch(void* const* d_in, const int* in_sizes, int n_in,
                              void* d_out, int out_size, void* d_ws, size_t ws_size,
                              hipStream_t stream) {
  if (ws_size < WS_FLOATS * sizeof(float)) return;  // workspace too small: fail visibly

  const float* x        = (const float*)d_in[0];
  const float* mask     = (const float*)d_in[1];
  const float* deltas   = (const float*)d_in[2];
  const float* last_obs = (const float*)d_in[3];
  const float* intervals= (const float*)d_in[4];
  const float* Wo  = (const float*)d_in[5];
  const float* bo  = (const float*)d_in[6];
  const float* Wip = (const float*)d_in[7];
  const float* bip = (const float*)d_in[8];
  const float* Wqkv= (const float*)d_in[9];
  const float* bqkv= (const float*)d_in[10];
  const float* Wao = (const float*)d_in[11];
  const float* bao = (const float*)d_in[12];
  const float* g1  = (const float*)d_in[13];
  const float* be1 = (const float*)d_in[14];
  const float* W1  = (const float*)d_in[15];
  const float* b1  = (const float*)d_in[16];
  const float* W2  = (const float*)d_in[17];
  const float* b2  = (const float*)d_in[18];
  const float* g2  = (const float*)d_in[19];
  const float* be2 = (const float*)d_in[20];
  const float* Wop1= (const float*)d_in[21];
  const float* bop1= (const float*)d_in[22];
  const float* wop2= (const float*)d_in[23];
  const float* bop2= (const float*)d_in[24];
  const float* Wdh = (const float*)d_in[25];
  const float* bdh = (const float*)d_in[26];
  const float* wdx = (const float*)d_in[27];
  const float* bdx = (const float*)d_in[28];
  const float* Wh  = (const float*)d_in[29];
  const float* bh  = (const float*)d_in[30];
  const float* Wfr = (const float*)d_in[31];
  const float* bfr = (const float*)d_in[32];
  const float* Wwc = (const float*)d_in[33];
  const float* bwc = (const float*)d_in[34];
  const float* Wih = (const float*)d_in[35];
  const float* bih = (const float*)d_in[36];
  const float* Whh = (const float*)d_in[37];
  const float* bhh = (const float*)d_in[38];

  float* out = (float*)d_out;
  float* ws  = (float*)d_ws;
  float* data  = ws + OFF_DATA;
  float* ctx   = ws + OFF_CTX;
  float* qkv   = ws + OFF_QKV;
  float* df    = ws + OFF_DF;
  float* gamH  = ws + OFF_GAMH;
  float* beta  = ws + OFF_BETA;
  float* t1    = ws + OFF_T1;
  float* h     = ws + OFF_H;
  float* dbar  = ws + OFF_DBAR;
  float* xh_p  = ws + OFF_XHP;
  float* gh_p  = ws + OFF_GHP;
  float* xu_p  = ws + OFF_XUP;
  float* xi    = ws + OFF_XI;
  float* gi_p  = ws + OFF_GIP;
  float* lossp = ws + OFF_LOSSP;
  float* den   = ws + OFF_DEN;
  float* sw    = ws + OFF_SW;
  float* lossacc = ws + OFF_LOSS;

  float* out_ximp = out;
  float* out_rec  = out + (size_t)Bb * Tt * Ff;
  float* out_h    = out + 2 * (size_t)Bb * Tt * Ff;
  float* out_loss = out_h + (size_t)Bb * Hh;

  const dim3 blk(256);

  // front end
  k_decay<<<dim3(2, 384), blk, 0, stream>>>(deltas, intervals, Wo, bo, df);
  k_proj<<<dim3(2, 384), blk, 0, stream>>>(last_obs, Wip, bip, data, 0);
  k_proj<<<dim3(2, 384), blk, 0, stream>>>(df, Wip, bip, data, 1);
  k_qkv<<<dim3(6, 768), blk, 0, stream>>>(data, Wqkv, bqkv, qkv);
  k_attn<<<dim3(6144), blk, 0, stream>>>(qkv, ctx);
  k_attnout<<<dim3(2, 768), blk, 0, stream>>>(ctx, Wao, bao, data);
  k_ln<<<dim3(12288), blk, 0, stream>>>(data, g1, be1);
  k_ff1<<<dim3(1, 768), blk, 0, stream>>>(data, W1, b1, t1);
  k_ff2<<<dim3(2, 768), blk, 0, stream>>>(t1, W2, b2, data);
  k_ln<<<dim3(12288), blk, 0, stream>>>(data, g2, be2);
  k_dbar<<<dim3(256), blk, 0, stream>>>(data, wop2, dbar, sw);
  k_h0<<<dim3(8, 4), blk, 0, stream>>>(dbar, Wop1, bop1, bop2, sw, h);

  // loop precomputes (overlay the dead qkv region)
  k_gamh<<<dim3(4, 384), blk, 0, stream>>>(deltas, Wdh, bdh, gamH);
  k_beta<<<dim3(2, 384), blk, 0, stream>>>(deltas, mask, wdx, bdx, Wwc, bwc, beta);
  k_den<<<dim3(96), blk, 0, stream>>>(mask, den);
  hipMemsetAsync(lossacc, 0, sizeof(float), stream);

  // sequential imputation loop
  for (int t = 0; t < 96; t++) {
    k_p1<<<dim3(32, 4, 2), blk, 0, stream>>>(h, gamH, Wh, Whh, xh_p, gh_p, t);
    k_p2<<<dim3(4, 4, 4), blk, 0, stream>>>(mask, x, xh_p, bh, Wfr, xu_p, t);
    k_p2b<<<dim3(256), blk, 0, stream>>>(xu_p, xh_p, bh, bfr, beta, mask, x,
                                         out_ximp, out_rec, xi, lossp, t);
    k_p3<<<dim3(24, 4, 2), blk, 0, stream>>>(xi, mask, Wih, gi_p, t);
    k_pd<<<dim3(513), blk, 0, stream>>>(h, gamH, gi_p, gh_p, bih, bhh, lossp, lossacc, den, t);
  }

  hipMemcpyAsync(out_h, h, (size_t)Bb * Hh * sizeof(float), hipMemcpyDeviceToDevice, stream);
  hipMemcpyAsync(out_loss, lossacc, sizeof(float), hipMemcpyDeviceToDevice, stream);
}